// Round 4
// baseline (523.342 us; speedup 1.0000x reference)
//
#include <hip/hip_runtime.h>
#include <hip/hip_bf16.h>
#include <cstdint>
#include <cstddef>

#define NH   16
#define HD   64
#define CD   1024
#define HARM 32
#define BSZ  2
#define LSEQ 2048
#define NROW (BSZ*LSEQ)   // 4096

typedef __attribute__((ext_vector_type(8))) short short8;     // 8 bf16 (A/B frag)
typedef __attribute__((ext_vector_type(16))) float float16v;  // 32x32 C frag

__device__ inline ushort bf16u(float f) {
    __hip_bfloat16 h = __float2bfloat16(f);
    return *(ushort*)&h;
}
__device__ inline unsigned pk2(float a, float b) {
    return (unsigned)bf16u(a) | ((unsigned)bf16u(b) << 16);
}
// C-frag register r -> row offset within 32-row tile
__device__ inline int crow(int r, int half) { return (r & 3) + 8 * (r >> 2) + 4 * half; }

union S8U { short8 v; uint2 u[2]; };

// Half-swap transform (verified in flash3): C-frag regs (as 8 packed uints,
// pk[j] = m-values {8*(j>>1)+4h+2*(j&1), +1}) -> one A/B-frag 16-k chunk cc.
__device__ inline short8 cfrag_chunk(const unsigned* pk, int cc, int h) {
    int gb2 = cc * 4;
    unsigned B0, B1, B2, B3;
    {
        unsigned v0 = pk[gb2], v1 = pk[gb2 + 2];
        unsigned send = h ? v0 : v1;
        unsigned rem = (unsigned)__shfl_xor((int)send, 32, 64);
        B0 = h ? rem : v0;
        B2 = h ? v1 : rem;
    }
    {
        unsigned v0 = pk[gb2 + 1], v1 = pk[gb2 + 3];
        unsigned send = h ? v0 : v1;
        unsigned rem = (unsigned)__shfl_xor((int)send, 32, 64);
        B1 = h ? rem : v0;
        B3 = h ? v1 : rem;
    }
    S8U bf;
    bf.u[0] = make_uint2(B0, B1);
    bf.u[1] = make_uint2(B2, B3);
    return bf.v;
}

// ---------------------------------------------------------------------------
// P1: prep — zero res_qkv+res_o+lbuf (contiguous) and OaccF; cast bases->bf16;
// w = amp*cos(phase)->bf16 (QSCALE folded into wq).
// ---------------------------------------------------------------------------
#define Z_A       147456u                    // (1.5M + 512K + 256K)/16
#define Z_OACCF   1048576u                   // 16 MB /16
#define C_BQKV    24576u                     // 96*1024/4
#define C_BO      8192u                      // 32*1024/4
#define C_W       32768u                     // 4*1024*32/4
#define P1_TOTAL  (Z_A + Z_OACCF + C_BQKV + C_BO + C_W)   // 1,261,568

__global__ void prep_kern(const float* __restrict__ bq, const float* __restrict__ bk,
                          const float* __restrict__ bv, const float* __restrict__ bo,
                          const float* __restrict__ pq, const float* __restrict__ aq,
                          const float* __restrict__ pk, const float* __restrict__ ak,
                          const float* __restrict__ pv, const float* __restrict__ av,
                          const float* __restrict__ po, const float* __restrict__ ao,
                          float* __restrict__ zeroA, float* __restrict__ OaccF,
                          ushort* __restrict__ bqkv, ushort* __restrict__ bob,
                          ushort* __restrict__ wqkv, ushort* __restrict__ wob) {
    unsigned i = blockIdx.x * 256 + threadIdx.x;
    float4 z = make_float4(0.f, 0.f, 0.f, 0.f);
    if (i < Z_A) { ((float4*)zeroA)[i] = z; return; }
    i -= Z_A;
    if (i < Z_OACCF) { ((float4*)OaccF)[i] = z; return; }
    i -= Z_OACCF;
    if (i < C_BQKV) {
        unsigned third = C_BQKV / 3;
        const float* src = (i < third) ? bq : (i < 2 * third) ? bk : bv;
        unsigned j = i % third;
        float4 v = ((const float4*)src)[j];
        ((ushort4*)bqkv)[i] = make_ushort4(bf16u(v.x), bf16u(v.y), bf16u(v.z), bf16u(v.w));
        return;
    }
    i -= C_BQKV;
    if (i < C_BO) {
        float4 v = ((const float4*)bo)[i];
        ((ushort4*)bob)[i] = make_ushort4(bf16u(v.x), bf16u(v.y), bf16u(v.z), bf16u(v.w));
        return;
    }
    i -= C_BO;
    {
        const float QSCALE = 0.125f * 1.44269504088896340736f;  // hd^-0.5 * log2e
        unsigned per = C_W / 4;
        unsigned proj = i / per, j = i % per;
        const float* ph = (proj == 0) ? pq : (proj == 1) ? pk : (proj == 2) ? pv : po;
        const float* am = (proj == 0) ? aq : (proj == 1) ? ak : (proj == 2) ? av : ao;
        float sc = (proj == 0) ? QSCALE : 1.0f;
        float4 p = ((const float4*)ph)[j];
        float4 a = ((const float4*)am)[j];
        ushort4 o = make_ushort4(bf16u(a.x * cosf(p.x) * sc), bf16u(a.y * cosf(p.y) * sc),
                                 bf16u(a.z * cosf(p.z) * sc), bf16u(a.w * cosf(p.w) * sc));
        if (proj < 3) ((ushort4*)wqkv)[proj * per + j] = o;
        else          ((ushort4*)wob)[j] = o;
    }
}

// ---------------------------------------------------------------------------
// P2: res_qkv[4096][96] += x @ bqkv^T  (split-K=8, fp32 x read + inline cast)
// jobs: mt(128) x nt(3) x kc(8) = 3072 -> 768 blocks
// ---------------------------------------------------------------------------
__global__ __launch_bounds__(256) void res_gemm(const float* __restrict__ x,
                                                const ushort* __restrict__ bqkv,
                                                float* __restrict__ res) {
    int wave = threadIdx.x >> 6, lane = threadIdx.x & 63;
    int l31 = lane & 31, half = lane >> 5;
    int job = blockIdx.x * 4 + wave;
    int kchunk = job & 7;
    int nt = (job >> 3) % 3;
    int mt = (job >> 3) / 3;
    const float* ap = x + (size_t)(mt * 32 + l31) * CD + kchunk * 128 + half * 8;
    const ushort* bp = bqkv + (size_t)(nt * 32 + l31) * CD + kchunk * 128 + half * 8;
    float16v c = {};
#pragma unroll
    for (int ks = 0; ks < 8; ks++) {
        float4 f0 = *(const float4*)(ap + ks * 16);
        float4 f1 = *(const float4*)(ap + ks * 16 + 4);
        S8U a;
        a.u[0] = make_uint2(pk2(f0.x, f0.y), pk2(f0.z, f0.w));
        a.u[1] = make_uint2(pk2(f1.x, f1.y), pk2(f1.z, f1.w));
        short8 b = *(const short8*)(bp + ks * 16);
        c = __builtin_amdgcn_mfma_f32_32x32x16_bf16(a.v, b, c, 0, 0, 0);
    }
    int col = nt * 32 + l31;
#pragma unroll
    for (int r = 0; r < 16; r++) {
        int row = mt * 32 + crow(r, half);
        atomicAdd(&res[(size_t)row * 96 + col], c[r]);
    }
}

// ---------------------------------------------------------------------------
// P3: qkv_fused — res block (32 rows) staged in LDS; q/k/v computed and stored
// DIRECTLY in MFMA-fragment-tiled layouts (repack eliminated).
//   qtile[bh][qt][kc][h][l31][8] : B[n=q-row][k=d]
//   ktile[bh][kblk][mt][kc][h][l31][8] : A[m=key][k=d]   (same as before)
//   vtile[bh][kblk][mt][kc][h][l31][8] : A[m=d][k=key]   (same as before)
// q,k use C=(A=w,B=res) -> lane=row; v uses C=(A=res,B=w) -> lane=ch.
// ---------------------------------------------------------------------------
__global__ __launch_bounds__(256) void qkv_fused(const float* __restrict__ res,
                                                 const ushort* __restrict__ wqkv,
                                                 ushort* __restrict__ qtile,
                                                 ushort* __restrict__ ktile,
                                                 ushort* __restrict__ vtile) {
    __shared__ float rs[32][100];                 // pitch 100 (4-way-free-ish)
    const int t = threadIdx.x, wave = t >> 6, lane = t & 63;
    const int l31 = lane & 31, h = lane >> 5;
    const int blk = blockIdx.x;                   // 128 = b(2) x l0q(64)
    const int b = blk >> 6, l0q = blk & 63;
    const int n0 = blk * 32;

    for (int i = t; i < 768; i += 256) {          // 32 rows x 24 float4
        int row = i / 24, c4 = i % 24;
        *(float4*)(&rs[row][c4 * 4]) = *(const float4*)(res + (size_t)(n0 + row) * 96 + c4 * 4);
    }
    __syncthreads();

    // res frags: lane=row l31, k = proj*32 + kc2*16 + h*8 + {0..7}
    short8 rf[3][2];
#pragma unroll
    for (int p = 0; p < 3; p++)
#pragma unroll
        for (int kc2 = 0; kc2 < 2; kc2++) {
            float4 f0 = *(const float4*)(&rs[l31][p * 32 + kc2 * 16 + h * 8]);
            float4 f1 = *(const float4*)(&rs[l31][p * 32 + kc2 * 16 + h * 8 + 4]);
            S8U a;
            a.u[0] = make_uint2(pk2(f0.x, f0.y), pk2(f0.z, f0.w));
            a.u[1] = make_uint2(pk2(f1.x, f1.y), pk2(f1.z, f1.w));
            rf[p][kc2] = a.v;
        }

    const int kblk = l0q >> 1, mtk = l0q & 1;
    for (int i = 0; i < 24; i++) {
        int nt = wave * 24 + i;
        int proj = nt >> 5, ntp = nt & 31;
        int head = ntp >> 1, sub = ntp & 1;
        const ushort* wp = wqkv + ((size_t)proj * CD + ntp * 32 + l31) * HARM;
        short8 wf0 = *(const short8*)(wp + h * 8);
        short8 wf1 = *(const short8*)(wp + 16 + h * 8);
        float16v c = {};
        if (proj < 2) {   // lane = row
            c = __builtin_amdgcn_mfma_f32_32x32x16_bf16(wf0, rf[proj][0], c, 0, 0, 0);
            c = __builtin_amdgcn_mfma_f32_32x32x16_bf16(wf1, rf[proj][1], c, 0, 0, 0);
        } else {          // lane = ch
            c = __builtin_amdgcn_mfma_f32_32x32x16_bf16(rf[2][0], wf0, c, 0, 0, 0);
            c = __builtin_amdgcn_mfma_f32_32x32x16_bf16(rf[2][1], wf1, c, 0, 0, 0);
        }
        unsigned pk[8];
#pragma unroll
        for (int j = 0; j < 8; j++) pk[j] = pk2(c[2 * j], c[2 * j + 1]);

        if (proj == 0) {
            ushort* base = qtile + (((size_t)(b * NH + head) * 64 + l0q)) * 2048;
#pragma unroll
            for (int cc = 0; cc < 2; cc++)
                *(short8*)(base + (sub * 2 + cc) * 512 + h * 256 + l31 * 8) =
                    cfrag_chunk(pk, cc, h);
        } else if (proj == 1) {
            ushort* base = ktile + ((size_t)(b * NH + head) * 32 + kblk) * 4096 + mtk * 2048;
#pragma unroll
            for (int cc = 0; cc < 2; cc++)
                *(short8*)(base + (sub * 2 + cc) * 512 + h * 256 + l31 * 8) =
                    cfrag_chunk(pk, cc, h);
        } else {
            ushort* base = vtile + ((size_t)(b * NH + head) * 32 + kblk) * 4096 + sub * 2048;
#pragma unroll
            for (int cc = 0; cc < 2; cc++)
                *(short8*)(base + (mtk * 2 + cc) * 512 + h * 256 + l31 * 8) =
                    cfrag_chunk(pk, cc, h);
        }
    }
}

// ---------------------------------------------------------------------------
// flash4: 32 q-rows/wave, K-split 2, no barriers, no LDS, no online max.
// All operands from fragment-tiled global (coalesced dwordx4, L1/L2).
// exp via v_exp_f32; row-sum l via ones-row MFMA (VALU -> MFMA pipe).
// Epilogue: fp32 half-swap -> coalesced atomics into fragment-tiled OaccF:
//   OaccF[b][qt][c16][h][l31][8],  c16 = head*4 + mt*2 + c.
// ---------------------------------------------------------------------------
__global__ __launch_bounds__(256) void flash4(const ushort* __restrict__ qtile,
                                              const ushort* __restrict__ ktile,
                                              const ushort* __restrict__ vtile,
                                              float* __restrict__ OaccF,
                                              float* __restrict__ lbuf) {
    const int wave = threadIdx.x >> 6, lane = threadIdx.x & 63;
    const int l31 = lane & 31, h = lane >> 5;
    const int bh = blockIdx.x >> 5;
    const int inner = blockIdx.x & 31;
    const int ksp = inner >> 4;
    const int qt = (inner & 15) * 4 + wave;       // 4 waves share the K/V stream
    const int fo = h * 256 + l31 * 8;

    const ushort* qtb = qtile + ((size_t)bh * 64 + qt) * 2048;
    short8 qf[4];
#pragma unroll
    for (int kc = 0; kc < 4; kc++) qf[kc] = *(const short8*)(qtb + kc * 512 + fo);

    const ushort* ktb = ktile + (size_t)bh * 32 * 4096;
    const ushort* vtb = vtile + (size_t)bh * 32 * 4096;

    S8U ones;
    ones.u[0] = make_uint2(0x3F803F80u, 0x3F803F80u);
    ones.u[1] = make_uint2(0x3F803F80u, 0x3F803F80u);

    float16v O0 = {}, O1 = {}, La = {};

    for (int kblk = ksp * 16; kblk < ksp * 16 + 16; kblk++) {
        const ushort* kb_ = ktb + (size_t)kblk * 4096;
        const ushort* vb_ = vtb + (size_t)kblk * 4096;
        short8 kf[2][4];
#pragma unroll
        for (int mt = 0; mt < 2; mt++)
#pragma unroll
            for (int kc = 0; kc < 4; kc++)
                kf[mt][kc] = *(const short8*)(kb_ + mt * 2048 + kc * 512 + fo);
        float16v s0 = {}, s1 = {};
#pragma unroll
        for (int kc = 0; kc < 4; kc++) {
            s0 = __builtin_amdgcn_mfma_f32_32x32x16_bf16(kf[0][kc], qf[kc], s0, 0, 0, 0);
            s1 = __builtin_amdgcn_mfma_f32_32x32x16_bf16(kf[1][kc], qf[kc], s1, 0, 0, 0);
        }
        short8 vf[2][4];
#pragma unroll
        for (int mt = 0; mt < 2; mt++)
#pragma unroll
            for (int kc = 0; kc < 4; kc++)
                vf[mt][kc] = *(const short8*)(vb_ + mt * 2048 + kc * 512 + fo);

        unsigned pk0[8], pk1[8];
#pragma unroll
        for (int j = 0; j < 8; j++) {
            pk0[j] = pk2(__builtin_amdgcn_exp2f(s0[2 * j]),
                         __builtin_amdgcn_exp2f(s0[2 * j + 1]));
            pk1[j] = pk2(__builtin_amdgcn_exp2f(s1[2 * j]),
                         __builtin_amdgcn_exp2f(s1[2 * j + 1]));
        }
#pragma unroll
        for (int kc = 0; kc < 4; kc++) {
            const unsigned* pkm = (kc < 2) ? pk0 : pk1;
            short8 bf = cfrag_chunk(pkm, kc & 1, h);
            La = __builtin_amdgcn_mfma_f32_32x32x16_bf16(ones.v, bf, La, 0, 0, 0);
            O0 = __builtin_amdgcn_mfma_f32_32x32x16_bf16(vf[0][kc], bf, O0, 0, 0, 0);
            O1 = __builtin_amdgcn_mfma_f32_32x32x16_bf16(vf[1][kc], bf, O1, 0, 0, 0);
        }
    }

    // ---- epilogue ----
    const int bb = bh >> 4, head = bh & (NH - 1);
    if (h == 0) atomicAdd(&lbuf[(size_t)bh * LSEQ + qt * 32 + l31], La[0]);

#pragma unroll
    for (int mt = 0; mt < 2; mt++) {
        float16v Ov = mt ? O1 : O0;
#pragma unroll
        for (int c = 0; c < 2; c++) {
            float outv[8];
#pragma unroll
            for (int i = 0; i < 4; i++) {
                float own_lo = Ov[c * 8 + i], own_hi = Ov[c * 8 + 4 + i];
                float send = h ? own_lo : own_hi;
                float rem = __shfl_xor(send, 32, 64);
                outv[i]     = h ? rem : own_lo;
                outv[4 + i] = h ? own_hi : rem;
            }
            int c16 = head * 4 + mt * 2 + c;
            float* dst = OaccF + ((((size_t)(bb * 64 + qt) * 64 + c16) * 2 + h) * 32 + l31) * 8;
#pragma unroll
            for (int j = 0; j < 8; j++) atomicAdd(dst + j, outv[j]);
        }
    }
}

// ---------------------------------------------------------------------------
// P5: res_o[4096][32] += normalize(OaccF) @ basis_o^T  (coalesced frag reads)
// jobs: mt(128) x kcg(16) = 2048 -> 512 blocks; 4 MFMA per wave (K=64 each).
// ---------------------------------------------------------------------------
__global__ __launch_bounds__(256) void reso_gemm(const float* __restrict__ OaccF,
                                                 const float* __restrict__ lbuf,
                                                 const ushort* __restrict__ bob,
                                                 float* __restrict__ res_o) {
    int wave = threadIdx.x >> 6, lane = threadIdx.x & 63;
    int l31 = lane & 31, h = lane >> 5;
    int job = blockIdx.x * 4 + wave;
    int kcg = job & 15, mt = job >> 4;
    int b = mt >> 6, qt = mt & 63;
    const float* abase = OaccF + (size_t)(b * 64 + qt) * 64 * 512;
    float16v c = {};
#pragma unroll
    for (int i = 0; i < 4; i++) {
        int c16 = kcg * 4 + i;
        int head = c16 >> 2;
        float invl = 1.0f / lbuf[((size_t)(b * NH + head)) * LSEQ + qt * 32 + l31];
        const float* ap = abase + (c16 * 2 + h) * 256 + l31 * 8;
        float4 f0 = *(const float4*)(ap);
        float4 f1 = *(const float4*)(ap + 4);
        S8U a;
        a.u[0] = make_uint2(pk2(f0.x * invl, f0.y * invl), pk2(f0.z * invl, f0.w * invl));
        a.u[1] = make_uint2(pk2(f1.x * invl, f1.y * invl), pk2(f1.z * invl, f1.w * invl));
        short8 bfr = *(const short8*)(bob + (size_t)l31 * CD + c16 * 16 + h * 8);
        c = __builtin_amdgcn_mfma_f32_32x32x16_bf16(a.v, bfr, c, 0, 0, 0);
    }
#pragma unroll
    for (int r = 0; r < 16; r++) {
        int row = mt * 32 + crow(r, h);
        atomicAdd(&res_o[(size_t)row * HARM + l31], c[r]);
    }
}

// ---------------------------------------------------------------------------
// P6: out[4096][1024] fp32 = res_o @ wo^T  (K=32)
// ---------------------------------------------------------------------------
__global__ __launch_bounds__(256) void out_gemm(const float* __restrict__ res_o,
                                                const ushort* __restrict__ wob,
                                                float* __restrict__ out) {
    int wave = threadIdx.x >> 6, lane = threadIdx.x & 63;
    int l31 = lane & 31, half = lane >> 5;
    int job = blockIdx.x * 4 + wave;
    int nt = job % 32, mt = job / 32;
    const float* ap = res_o + (size_t)(mt * 32 + l31) * HARM + half * 8;
    const ushort* bp = wob + (size_t)(nt * 32 + l31) * HARM + half * 8;
    float16v c = {};
#pragma unroll
    for (int ks = 0; ks < 2; ks++) {
        float4 f0 = *(const float4*)(ap + ks * 16);
        float4 f1 = *(const float4*)(ap + ks * 16 + 4);
        S8U a;
        a.u[0] = make_uint2(pk2(f0.x, f0.y), pk2(f0.z, f0.w));
        a.u[1] = make_uint2(pk2(f1.x, f1.y), pk2(f1.z, f1.w));
        short8 b = *(const short8*)(bp + ks * 16);
        c = __builtin_amdgcn_mfma_f32_32x32x16_bf16(a.v, b, c, 0, 0, 0);
    }
    int col = nt * 32 + l31;
#pragma unroll
    for (int r = 0; r < 16; r++) {
        int row = mt * 32 + crow(r, half);
        out[(size_t)row * CD + col] = c[r];
    }
}

// ---------------------------------------------------------------------------
extern "C" void kernel_launch(void* const* d_in, const int* in_sizes, int n_in,
                              void* d_out, int out_size, void* d_ws, size_t ws_size,
                              hipStream_t stream) {
    const float* x  = (const float*)d_in[0];
    const float* bq = (const float*)d_in[1];
    const float* pq = (const float*)d_in[2];
    const float* aq = (const float*)d_in[3];
    const float* bk = (const float*)d_in[4];
    const float* pk = (const float*)d_in[5];
    const float* ak = (const float*)d_in[6];
    const float* bv = (const float*)d_in[7];
    const float* pv = (const float*)d_in[8];
    const float* av = (const float*)d_in[9];
    const float* bo = (const float*)d_in[10];
    const float* po = (const float*)d_in[11];
    const float* ao = (const float*)d_in[12];

    char* ws = (char*)d_ws;
    ushort* bqkv   = (ushort*)(ws + 0);              // 192 KB
    ushort* bob    = (ushort*)(ws + 196608);         //  64 KB
    ushort* wqkv   = (ushort*)(ws + 262144);         // 192 KB
    ushort* wob    = (ushort*)(ws + 458752);         //  64 KB
    float*  res_qkv= (float*)(ws + 524288);          // 1.5 MB  ┐
    float*  res_o  = (float*)(ws + 2097152);         // 512 KB  ├ zeroA (contig)
    float*  lbuf   = (float*)(ws + 2621440);         // 256 KB  ┘
    ushort* qtile  = (ushort*)(ws + 2883584);        //   8 MB
    ushort* ktile  = (ushort*)(ws + 11272192);       //   8 MB
    ushort* vtile  = (ushort*)(ws + 19660800);       //   8 MB
    float*  OaccF  = (float*)(ws + 28049408);        //  16 MB  -> total ~44.8 MB
    float*  zeroA  = res_qkv;

    prep_kern<<<P1_TOTAL / 256, 256, 0, stream>>>(bq, bk, bv, bo,
                                                  pq, aq, pk, ak, pv, av, po, ao,
                                                  zeroA, OaccF, bqkv, bob, wqkv, wob);
    res_gemm<<<768, 256, 0, stream>>>(x, bqkv, res_qkv);
    qkv_fused<<<128, 256, 0, stream>>>(res_qkv, wqkv, qtile, ktile, vtile);
    flash4<<<BSZ * NH * 32, 256, 0, stream>>>(qtile, ktile, vtile, OaccF, lbuf);
    reso_gemm<<<512, 256, 0, stream>>>(OaccF, lbuf, bob, res_o);
    out_gemm<<<1024, 256, 0, stream>>>(res_o, wob, (float*)d_out);
}

// Round 5
// 239.069 us; speedup vs baseline: 2.1891x; 2.1891x over previous
//
#include <hip/hip_runtime.h>
#include <hip/hip_bf16.h>
#include <cstdint>
#include <cstddef>

#define NH   16
#define HD   64
#define CD   1024
#define HARM 32
#define BSZ  2
#define LSEQ 2048
#define NROW (BSZ*LSEQ)   // 4096

typedef __attribute__((ext_vector_type(8))) short short8;     // 8 bf16 (A/B frag)
typedef __attribute__((ext_vector_type(16))) float float16v;  // 32x32 C frag

__device__ inline ushort bf16u(float f) {
    __hip_bfloat16 h = __float2bfloat16(f);
    return *(ushort*)&h;
}
__device__ inline unsigned pk2(float a, float b) {
    return (unsigned)bf16u(a) | ((unsigned)bf16u(b) << 16);
}
// C-frag register r -> row offset within 32-row tile
__device__ inline int crow(int r, int half) { return (r & 3) + 8 * (r >> 2) + 4 * half; }

union S8U { short8 v; uint2 u[2]; };

// Half-swap transform (verified flash3/flash4): C-frag regs (8 packed uints,
// pk[j] = m-values {8*(j>>1)+4h+2*(j&1), +1}) -> one A/B-frag 16-k chunk cc.
__device__ inline short8 cfrag_chunk(const unsigned* pk, int cc, int h) {
    int gb2 = cc * 4;
    unsigned B0, B1, B2, B3;
    {
        unsigned v0 = pk[gb2], v1 = pk[gb2 + 2];
        unsigned send = h ? v0 : v1;
        unsigned rem = (unsigned)__shfl_xor((int)send, 32, 64);
        B0 = h ? rem : v0;
        B2 = h ? v1 : rem;
    }
    {
        unsigned v0 = pk[gb2 + 1], v1 = pk[gb2 + 3];
        unsigned send = h ? v0 : v1;
        unsigned rem = (unsigned)__shfl_xor((int)send, 32, 64);
        B1 = h ? rem : v0;
        B3 = h ? v1 : rem;
    }
    S8U bf;
    bf.u[0] = make_uint2(B0, B1);
    bf.u[1] = make_uint2(B2, B3);
    return bf.v;
}

// ---------------------------------------------------------------------------
// P1: prep — zero res_qkv+res_o+lbuf (contiguous) and OaccF; cast bases->bf16;
// w = amp*cos(phase)->bf16 (QSCALE folded into wq).
// ---------------------------------------------------------------------------
#define Z_A       147456u                    // (1.5M + 512K + 256K)/16
#define Z_OACCF   1048576u                   // 16 MB /16
#define C_BQKV    24576u                     // 96*1024/4
#define C_BO      8192u                      // 32*1024/4
#define C_W       32768u                     // 4*1024*32/4
#define P1_TOTAL  (Z_A + Z_OACCF + C_BQKV + C_BO + C_W)

__global__ void prep_kern(const float* __restrict__ bq, const float* __restrict__ bk,
                          const float* __restrict__ bv, const float* __restrict__ bo,
                          const float* __restrict__ pq, const float* __restrict__ aq,
                          const float* __restrict__ pk, const float* __restrict__ ak,
                          const float* __restrict__ pv, const float* __restrict__ av,
                          const float* __restrict__ po, const float* __restrict__ ao,
                          float* __restrict__ zeroA, float* __restrict__ OaccF,
                          ushort* __restrict__ bqkv, ushort* __restrict__ bob,
                          ushort* __restrict__ wqkv, ushort* __restrict__ wob) {
    unsigned i = blockIdx.x * 256 + threadIdx.x;
    float4 z = make_float4(0.f, 0.f, 0.f, 0.f);
    if (i < Z_A) { ((float4*)zeroA)[i] = z; return; }
    i -= Z_A;
    if (i < Z_OACCF) { ((float4*)OaccF)[i] = z; return; }
    i -= Z_OACCF;
    if (i < C_BQKV) {
        unsigned third = C_BQKV / 3;
        const float* src = (i < third) ? bq : (i < 2 * third) ? bk : bv;
        unsigned j = i % third;
        float4 v = ((const float4*)src)[j];
        ((ushort4*)bqkv)[i] = make_ushort4(bf16u(v.x), bf16u(v.y), bf16u(v.z), bf16u(v.w));
        return;
    }
    i -= C_BQKV;
    if (i < C_BO) {
        float4 v = ((const float4*)bo)[i];
        ((ushort4*)bob)[i] = make_ushort4(bf16u(v.x), bf16u(v.y), bf16u(v.z), bf16u(v.w));
        return;
    }
    i -= C_BO;
    {
        const float QSCALE = 0.125f * 1.44269504088896340736f;  // hd^-0.5 * log2e
        unsigned per = C_W / 4;
        unsigned proj = i / per, j = i % per;
        const float* ph = (proj == 0) ? pq : (proj == 1) ? pk : (proj == 2) ? pv : po;
        const float* am = (proj == 0) ? aq : (proj == 1) ? ak : (proj == 2) ? av : ao;
        float sc = (proj == 0) ? QSCALE : 1.0f;
        float4 p = ((const float4*)ph)[j];
        float4 a = ((const float4*)am)[j];
        ushort4 o = make_ushort4(bf16u(a.x * cosf(p.x) * sc), bf16u(a.y * cosf(p.y) * sc),
                                 bf16u(a.z * cosf(p.z) * sc), bf16u(a.w * cosf(p.w) * sc));
        if (proj < 3) ((ushort4*)wqkv)[proj * per + j] = o;
        else          ((ushort4*)wob)[j] = o;
    }
}

// ---------------------------------------------------------------------------
// P2: res_qkv[4096][96] += x @ bqkv^T  (split-K=8, fp32 x read + inline cast)
// ---------------------------------------------------------------------------
__global__ __launch_bounds__(256) void res_gemm(const float* __restrict__ x,
                                                const ushort* __restrict__ bqkv,
                                                float* __restrict__ res) {
    int wave = threadIdx.x >> 6, lane = threadIdx.x & 63;
    int l31 = lane & 31, half = lane >> 5;
    int job = blockIdx.x * 4 + wave;
    int kchunk = job & 7;
    int nt = (job >> 3) % 3;
    int mt = (job >> 3) / 3;
    const float* ap = x + (size_t)(mt * 32 + l31) * CD + kchunk * 128 + half * 8;
    const ushort* bp = bqkv + (size_t)(nt * 32 + l31) * CD + kchunk * 128 + half * 8;
    float16v c = {};
#pragma unroll
    for (int ks = 0; ks < 8; ks++) {
        float4 f0 = *(const float4*)(ap + ks * 16);
        float4 f1 = *(const float4*)(ap + ks * 16 + 4);
        S8U a;
        a.u[0] = make_uint2(pk2(f0.x, f0.y), pk2(f0.z, f0.w));
        a.u[1] = make_uint2(pk2(f1.x, f1.y), pk2(f1.z, f1.w));
        short8 b = *(const short8*)(bp + ks * 16);
        c = __builtin_amdgcn_mfma_f32_32x32x16_bf16(a.v, b, c, 0, 0, 0);
    }
    int col = nt * 32 + l31;
#pragma unroll
    for (int r = 0; r < 16; r++) {
        int row = mt * 32 + crow(r, half);
        atomicAdd(&res[(size_t)row * 96 + col], c[r]);
    }
}

// ---------------------------------------------------------------------------
// P3: qkv_fused — res block (32 rows) staged in LDS; q/k/v computed and stored
// DIRECTLY in MFMA-fragment-tiled layouts.  4-way output-segment split for
// occupancy: 512 blocks, each wave handles 6 of 96 output channel-tiles.
//   qtile[bh][qt][kc][h][l31][8] : B[n=q-row][k=d]
//   ktile[bh][kblk][mt][kc][h][l31][8] : A[m=key][k=d]
//   vtile[bh][kblk][mt][kc][h][l31][8] : A[m=d][k=key]
// ---------------------------------------------------------------------------
__global__ __launch_bounds__(256) void qkv_fused(const float* __restrict__ res,
                                                 const ushort* __restrict__ wqkv,
                                                 ushort* __restrict__ qtile,
                                                 ushort* __restrict__ ktile,
                                                 ushort* __restrict__ vtile) {
    __shared__ float rs[32][100];
    const int t = threadIdx.x, wave = t >> 6, lane = t & 63;
    const int l31 = lane & 31, h = lane >> 5;
    const int blk = blockIdx.x;                   // 512 = (b x l0q)(128) x seg(4)
    const int seg = blk & 3, rest = blk >> 2;
    const int b = rest >> 6, l0q = rest & 63;
    const int n0 = rest * 32;

    for (int i = t; i < 768; i += 256) {          // 32 rows x 24 float4
        int row = i / 24, c4 = i % 24;
        *(float4*)(&rs[row][c4 * 4]) = *(const float4*)(res + (size_t)(n0 + row) * 96 + c4 * 4);
    }
    __syncthreads();

    short8 rf[3][2];
#pragma unroll
    for (int p = 0; p < 3; p++)
#pragma unroll
        for (int kc2 = 0; kc2 < 2; kc2++) {
            float4 f0 = *(const float4*)(&rs[l31][p * 32 + kc2 * 16 + h * 8]);
            float4 f1 = *(const float4*)(&rs[l31][p * 32 + kc2 * 16 + h * 8 + 4]);
            S8U a;
            a.u[0] = make_uint2(pk2(f0.x, f0.y), pk2(f0.z, f0.w));
            a.u[1] = make_uint2(pk2(f1.x, f1.y), pk2(f1.z, f1.w));
            rf[p][kc2] = a.v;
        }

    const int kblk = l0q >> 1, mtk = l0q & 1;
    for (int i = 0; i < 6; i++) {
        int nt = (seg * 4 + wave) * 6 + i;
        int proj = nt >> 5, ntp = nt & 31;
        int head = ntp >> 1, sub = ntp & 1;
        const ushort* wp = wqkv + ((size_t)proj * CD + ntp * 32 + l31) * HARM;
        short8 wf0 = *(const short8*)(wp + h * 8);
        short8 wf1 = *(const short8*)(wp + 16 + h * 8);
        float16v c = {};
        if (proj < 2) {   // lane = row
            c = __builtin_amdgcn_mfma_f32_32x32x16_bf16(wf0, rf[proj][0], c, 0, 0, 0);
            c = __builtin_amdgcn_mfma_f32_32x32x16_bf16(wf1, rf[proj][1], c, 0, 0, 0);
        } else {          // lane = ch
            c = __builtin_amdgcn_mfma_f32_32x32x16_bf16(rf[2][0], wf0, c, 0, 0, 0);
            c = __builtin_amdgcn_mfma_f32_32x32x16_bf16(rf[2][1], wf1, c, 0, 0, 0);
        }
        unsigned pk[8];
#pragma unroll
        for (int j = 0; j < 8; j++) pk[j] = pk2(c[2 * j], c[2 * j + 1]);

        if (proj == 0) {
            ushort* base = qtile + (((size_t)(b * NH + head) * 64 + l0q)) * 2048;
#pragma unroll
            for (int cc = 0; cc < 2; cc++)
                *(short8*)(base + (sub * 2 + cc) * 512 + h * 256 + l31 * 8) =
                    cfrag_chunk(pk, cc, h);
        } else if (proj == 1) {
            ushort* base = ktile + ((size_t)(b * NH + head) * 32 + kblk) * 4096 + mtk * 2048;
#pragma unroll
            for (int cc = 0; cc < 2; cc++)
                *(short8*)(base + (sub * 2 + cc) * 512 + h * 256 + l31 * 8) =
                    cfrag_chunk(pk, cc, h);
        } else {
            ushort* base = vtile + ((size_t)(b * NH + head) * 32 + kblk) * 4096 + sub * 2048;
#pragma unroll
            for (int cc = 0; cc < 2; cc++)
                *(short8*)(base + (mtk * 2 + cc) * 512 + h * 256 + l31 * 8) =
                    cfrag_chunk(pk, cc, h);
        }
    }
}

// ---------------------------------------------------------------------------
// flash5: flash4 loop (verified) + RAW C-frag epilogue with lanes contiguous.
//   OaccF[b][head][qt][mt][r][h][l31]  (strides 1024/64/32/1 within a qt blk
//   of 2048 floats) — each atomic instruction covers 256 contiguous bytes.
// ---------------------------------------------------------------------------
__global__ __launch_bounds__(256) void flash5(const ushort* __restrict__ qtile,
                                              const ushort* __restrict__ ktile,
                                              const ushort* __restrict__ vtile,
                                              float* __restrict__ OaccF,
                                              float* __restrict__ lbuf) {
    const int wave = threadIdx.x >> 6, lane = threadIdx.x & 63;
    const int l31 = lane & 31, h = lane >> 5;
    const int bh = blockIdx.x >> 5;
    const int inner = blockIdx.x & 31;
    const int ksp = inner >> 4;
    const int qt = (inner & 15) * 4 + wave;       // 4 waves share the K/V stream
    const int fo = h * 256 + l31 * 8;

    const ushort* qtb = qtile + ((size_t)bh * 64 + qt) * 2048;
    short8 qf[4];
#pragma unroll
    for (int kc = 0; kc < 4; kc++) qf[kc] = *(const short8*)(qtb + kc * 512 + fo);

    const ushort* ktb = ktile + (size_t)bh * 32 * 4096;
    const ushort* vtb = vtile + (size_t)bh * 32 * 4096;

    S8U ones;
    ones.u[0] = make_uint2(0x3F803F80u, 0x3F803F80u);
    ones.u[1] = make_uint2(0x3F803F80u, 0x3F803F80u);

    float16v O0 = {}, O1 = {}, La = {};

    for (int kblk = ksp * 16; kblk < ksp * 16 + 16; kblk++) {
        const ushort* kb_ = ktb + (size_t)kblk * 4096;
        const ushort* vb_ = vtb + (size_t)kblk * 4096;
        short8 kf[2][4];
#pragma unroll
        for (int mt = 0; mt < 2; mt++)
#pragma unroll
            for (int kc = 0; kc < 4; kc++)
                kf[mt][kc] = *(const short8*)(kb_ + mt * 2048 + kc * 512 + fo);
        float16v s0 = {}, s1 = {};
#pragma unroll
        for (int kc = 0; kc < 4; kc++) {
            s0 = __builtin_amdgcn_mfma_f32_32x32x16_bf16(kf[0][kc], qf[kc], s0, 0, 0, 0);
            s1 = __builtin_amdgcn_mfma_f32_32x32x16_bf16(kf[1][kc], qf[kc], s1, 0, 0, 0);
        }
        short8 vf[2][4];
#pragma unroll
        for (int mt = 0; mt < 2; mt++)
#pragma unroll
            for (int kc = 0; kc < 4; kc++)
                vf[mt][kc] = *(const short8*)(vb_ + mt * 2048 + kc * 512 + fo);

        unsigned pk0[8], pk1[8];
#pragma unroll
        for (int j = 0; j < 8; j++) {
            pk0[j] = pk2(__builtin_amdgcn_exp2f(s0[2 * j]),
                         __builtin_amdgcn_exp2f(s0[2 * j + 1]));
            pk1[j] = pk2(__builtin_amdgcn_exp2f(s1[2 * j]),
                         __builtin_amdgcn_exp2f(s1[2 * j + 1]));
        }
#pragma unroll
        for (int kc = 0; kc < 4; kc++) {
            const unsigned* pkm = (kc < 2) ? pk0 : pk1;
            short8 bf = cfrag_chunk(pkm, kc & 1, h);
            La = __builtin_amdgcn_mfma_f32_32x32x16_bf16(ones.v, bf, La, 0, 0, 0);
            O0 = __builtin_amdgcn_mfma_f32_32x32x16_bf16(vf[0][kc], bf, O0, 0, 0, 0);
            O1 = __builtin_amdgcn_mfma_f32_32x32x16_bf16(vf[1][kc], bf, O1, 0, 0, 0);
        }
    }

    // ---- epilogue: raw C-frag dump, 64 lanes contiguous per atomic ----
    const int bb = bh >> 4, head = bh & (NH - 1);
    if (h == 0) atomicAdd(&lbuf[(size_t)bh * LSEQ + qt * 32 + l31], La[0]);

    float* dstbase = OaccF + ((size_t)(bb * NH + head) * 64 + qt) * 2048 + h * 32 + l31;
#pragma unroll
    for (int r = 0; r < 16; r++) {
        atomicAdd(dstbase + r * 64, O0[r]);
        atomicAdd(dstbase + 1024 + r * 64, O1[r]);
    }
}

// ---------------------------------------------------------------------------
// P5: res_o[4096][32] += normalize(OaccF) @ basis_o^T
// jobs: mtq(128) x head(16) = 2048 -> 512 blocks; K=64 per job (4 MFMA).
// A-frags reconstructed from raw C-frag layout via crow^-1 index math.
// ---------------------------------------------------------------------------
__global__ __launch_bounds__(256) void reso_gemm(const float* __restrict__ OaccF,
                                                 const float* __restrict__ lbuf,
                                                 const ushort* __restrict__ bob,
                                                 float* __restrict__ res_o) {
    int wave = threadIdx.x >> 6, lane = threadIdx.x & 63;
    int l31 = lane & 31, h = lane >> 5;
    int job = blockIdx.x * 4 + wave;
    int head = job & 15, mtq = job >> 4;
    int b = mtq >> 6, qt = mtq & 63;
    const float* abase = OaccF + ((size_t)(b * NH + head) * 64 + qt) * 2048;
    float invl = 1.0f / lbuf[((size_t)(b * NH + head)) * LSEQ + qt * 32 + l31];
    float16v c = {};
#pragma unroll
    for (int kc = 0; kc < 4; kc++) {
        float av[8];
#pragma unroll
        for (int j = 0; j < 8; j++) {
            int cch = kc * 16 + h * 8 + j;        // channel within head (0..63)
            int cc = cch & 31, mtc = cch >> 5;
            int hp = (cc >> 2) & 1, rr = (cc & 3) + 4 * (cc >> 3);
            av[j] = abase[((mtc * 16 + rr) * 2 + hp) * 32 + l31] * invl;
        }
        S8U a;
        a.u[0] = make_uint2(pk2(av[0], av[1]), pk2(av[2], av[3]));
        a.u[1] = make_uint2(pk2(av[4], av[5]), pk2(av[6], av[7]));
        short8 bfr = *(const short8*)(bob + (size_t)l31 * CD + head * 64 + kc * 16 + h * 8);
        c = __builtin_amdgcn_mfma_f32_32x32x16_bf16(a.v, bfr, c, 0, 0, 0);
    }
#pragma unroll
    for (int r = 0; r < 16; r++) {
        int row = mtq * 32 + crow(r, h);
        atomicAdd(&res_o[(size_t)row * HARM + l31], c[r]);
    }
}

// ---------------------------------------------------------------------------
// P6: out[4096][1024] fp32 = res_o @ wo^T  (K=32)
// ---------------------------------------------------------------------------
__global__ __launch_bounds__(256) void out_gemm(const float* __restrict__ res_o,
                                                const ushort* __restrict__ wob,
                                                float* __restrict__ out) {
    int wave = threadIdx.x >> 6, lane = threadIdx.x & 63;
    int l31 = lane & 31, half = lane >> 5;
    int job = blockIdx.x * 4 + wave;
    int nt = job % 32, mt = job / 32;
    const float* ap = res_o + (size_t)(mt * 32 + l31) * HARM + half * 8;
    const ushort* bp = wob + (size_t)(nt * 32 + l31) * HARM + half * 8;
    float16v c = {};
#pragma unroll
    for (int ks = 0; ks < 2; ks++) {
        float4 f0 = *(const float4*)(ap + ks * 16);
        float4 f1 = *(const float4*)(ap + ks * 16 + 4);
        S8U a;
        a.u[0] = make_uint2(pk2(f0.x, f0.y), pk2(f0.z, f0.w));
        a.u[1] = make_uint2(pk2(f1.x, f1.y), pk2(f1.z, f1.w));
        short8 b = *(const short8*)(bp + ks * 16);
        c = __builtin_amdgcn_mfma_f32_32x32x16_bf16(a.v, b, c, 0, 0, 0);
    }
    int col = nt * 32 + l31;
#pragma unroll
    for (int r = 0; r < 16; r++) {
        int row = mt * 32 + crow(r, half);
        out[(size_t)row * CD + col] = c[r];
    }
}

// ---------------------------------------------------------------------------
extern "C" void kernel_launch(void* const* d_in, const int* in_sizes, int n_in,
                              void* d_out, int out_size, void* d_ws, size_t ws_size,
                              hipStream_t stream) {
    const float* x  = (const float*)d_in[0];
    const float* bq = (const float*)d_in[1];
    const float* pq = (const float*)d_in[2];
    const float* aq = (const float*)d_in[3];
    const float* bk = (const float*)d_in[4];
    const float* pk = (const float*)d_in[5];
    const float* ak = (const float*)d_in[6];
    const float* bv = (const float*)d_in[7];
    const float* pv = (const float*)d_in[8];
    const float* av = (const float*)d_in[9];
    const float* bo = (const float*)d_in[10];
    const float* po = (const float*)d_in[11];
    const float* ao = (const float*)d_in[12];

    char* ws = (char*)d_ws;
    ushort* bqkv   = (ushort*)(ws + 0);              // 192 KB
    ushort* bob    = (ushort*)(ws + 196608);         //  64 KB
    ushort* wqkv   = (ushort*)(ws + 262144);         // 192 KB
    ushort* wob    = (ushort*)(ws + 458752);         //  64 KB
    float*  res_qkv= (float*)(ws + 524288);          // 1.5 MB  ┐
    float*  res_o  = (float*)(ws + 2097152);         // 512 KB  ├ zeroA (contig)
    float*  lbuf   = (float*)(ws + 2621440);         // 256 KB  ┘
    ushort* qtile  = (ushort*)(ws + 2883584);        //   8 MB
    ushort* ktile  = (ushort*)(ws + 11272192);       //   8 MB
    ushort* vtile  = (ushort*)(ws + 19660800);       //   8 MB
    float*  OaccF  = (float*)(ws + 28049408);        //  16 MB  -> total ~44.8 MB
    float*  zeroA  = res_qkv;

    prep_kern<<<P1_TOTAL / 256, 256, 0, stream>>>(bq, bk, bv, bo,
                                                  pq, aq, pk, ak, pv, av, po, ao,
                                                  zeroA, OaccF, bqkv, bob, wqkv, wob);
    res_gemm<<<768, 256, 0, stream>>>(x, bqkv, res_qkv);
    qkv_fused<<<512, 256, 0, stream>>>(res_qkv, wqkv, qtile, ktile, vtile);
    flash5<<<BSZ * NH * 32, 256, 0, stream>>>(qtile, ktile, vtile, OaccF, lbuf);
    reso_gemm<<<512, 256, 0, stream>>>(OaccF, lbuf, bob, res_o);
    out_gemm<<<1024, 256, 0, stream>>>(res_o, wob, (float*)d_out);
}